// Round 4
// baseline (498.050 us; speedup 1.0000x reference)
//
#include <hip/hip_runtime.h>

#define SEQ 1024
#define BATCH 512
#define NTAGS 64

// One wave per chain, linear-space forward recurrence:
//   beta'_j = (sum_i beta_i * expT[i][j]) * exp(em[t,j])
// Broadcast of beta_i to all lanes is done through SGPRs via v_readlane
// (64 readlane + 64 fma, 4 independent accumulators) -- NO LDS on the
// critical path, so the per-step cost is pure VALU issue (~280 cyc),
// not LDS round-trip latency (~663 cyc in the R2 LDS version).
// Renorm: divide by 2-step-stale beta_0 (via readfirstlane) folded into the
// exp(em) factor once per 4-step group; M accumulates log of the scales.
// Numerator fused via wave-uniform LDS trans reads + one shfl per step,
// all consumed off the critical path (DS pipe is otherwise idle).
__global__ __launch_bounds__(64)
void crf_kernel(const float* __restrict__ em,
                const int* __restrict__ tags,
                const int* __restrict__ mask,
                const float* __restrict__ startT,
                const float* __restrict__ endT,
                const float* __restrict__ trans,
                float* __restrict__ out)
{
    const int b = blockIdx.x;
    const int j = threadIdx.x;  // tag index 0..63

    __shared__ float trans_sh[NTAGS * NTAGS];

    // expT column j in registers (64 VGPRs); raw trans into LDS for the
    // numerator lookups.
    float colf[NTAGS];
#pragma unroll
    for (int i = 0; i < NTAGS; ++i) {
        float tv = trans[i * NTAGS + j];
        trans_sh[i * NTAGS + j] = tv;
        colf[i] = __expf(tv);
    }

    const float eend = __expf(endT[j]);

    // chain length = sum of this chain's (prefix) mask column
    int lsum = 0;
#pragma unroll
    for (int k = 0; k < SEQ / 64; ++k)
        lsum += mask[(k * 64 + j) * BATCH + b];
#pragma unroll
    for (int off = 32; off > 0; off >>= 1)
        lsum += __shfl_xor(lsum, off);
    const int L = lsum;  // in [1, SEQ]

    // ---- t = 0 ----
    float em0   = em[(size_t)b * NTAGS + j];
    float a0j   = startT[j] + em0;
    float M     = __shfl(a0j, 0);
    float beta  = __expf(a0j - M);

    int   prev = tags[b];
    float num  = startT[prev] + __shfl(em0, prev);

    asm volatile("" ::: "memory");  // trans_sh written (single wave, in-order DS)

    // s_j = sum_i beta_i * expT[i][j], beta broadcast through SGPRs.
#define DOT_RL(SVAR)                                                      \
    {                                                                     \
        float s0 = 0.f, s1 = 0.f, s2 = 0.f, s3 = 0.f;                     \
        _Pragma("unroll")                                                 \
        for (int i = 0; i < NTAGS; i += 4) {                              \
            float b0 = __uint_as_float(__builtin_amdgcn_readlane(__float_as_uint(beta), i + 0)); \
            float b1 = __uint_as_float(__builtin_amdgcn_readlane(__float_as_uint(beta), i + 1)); \
            float b2 = __uint_as_float(__builtin_amdgcn_readlane(__float_as_uint(beta), i + 2)); \
            float b3 = __uint_as_float(__builtin_amdgcn_readlane(__float_as_uint(beta), i + 3)); \
            s0 = fmaf(b0, colf[i + 0], s0);                               \
            s1 = fmaf(b1, colf[i + 1], s1);                               \
            s2 = fmaf(b2, colf[i + 2], s2);                               \
            s3 = fmaf(b3, colf[i + 3], s3);                               \
        }                                                                 \
        SVAR = (s0 + s1) + (s2 + s3);                                     \
    }

    int t = 1;

    // distance-4 prefetch
    float em_c[4]; int tg_c[4];
#pragma unroll
    for (int u = 0; u < 4; ++u) {
        int tt = min(t + u, SEQ - 1);
        em_c[u] = em[((size_t)tt * BATCH + b) * NTAGS + j];
        tg_c[u] = tags[tt * BATCH + b];
    }

    while (t + 3 <= L - 1) {
        // prefetch next group (consumed one full group later)
        float em_n[4]; int tg_n[4];
#pragma unroll
        for (int u = 0; u < 4; ++u) {
            int tt = min(t + 4 + u, SEQ - 1);
            em_n[u] = em[((size_t)tt * BATCH + b) * NTAGS + j];
            tg_n[u] = tags[tt * BATCH + b];
        }

        // off-path: exp of this group's emissions
        float eem[4];
#pragma unroll
        for (int u = 0; u < 4; ++u) eem[u] = __expf(em_c[u]);

        // off-path numerator lookups (LDS + shfl on the otherwise-idle DS pipe)
        float tr0 = trans_sh[prev    * NTAGS + tg_c[0]];
        float tr1 = trans_sh[tg_c[0] * NTAGS + tg_c[1]];
        float tr2 = trans_sh[tg_c[1] * NTAGS + tg_c[2]];
        float tr3 = trans_sh[tg_c[2] * NTAGS + tg_c[3]];
        float ge0 = __shfl(em_c[0], tg_c[0]);
        float ge1 = __shfl(em_c[1], tg_c[1]);
        float ge2 = __shfl(em_c[2], tg_c[2]);
        float ge3 = __shfl(em_c[3], tg_c[3]);

        float s;

        // u = 0
        DOT_RL(s); beta = s * eem[0];
        // u = 1
        DOT_RL(s); beta = s * eem[1];
        float rs = __uint_as_float(__builtin_amdgcn_readfirstlane(__float_as_uint(beta)));
        // u = 2
        DOT_RL(s); beta = s * eem[2];
        float rinv = 1.0f / rs;            // off-path
        float lrs  = __logf(rs);           // off-path
        // u = 3: fold renorm into the emission factor
        DOT_RL(s); beta = s * (eem[3] * rinv);
        M += lrs;

        num += (tr0 + ge0) + (tr1 + ge1) + (tr2 + ge2) + (tr3 + ge3);
        prev = tg_c[3];

#pragma unroll
        for (int u = 0; u < 4; ++u) { em_c[u] = em_n[u]; tg_c[u] = tg_n[u]; }
        t += 4;
    }

    // tail (<=3 steps), per-step renorm
    for (; t <= L - 1; ++t) {
        float emt = em[((size_t)t * BATCH + b) * NTAGS + j];
        int   cur = tags[t * BATCH + b];
        num += trans_sh[prev * NTAGS + cur] + __shfl(emt, cur);
        prev = cur;

        float s;
        DOT_RL(s);
        beta = s * __expf(emt);
        float r = __uint_as_float(__builtin_amdgcn_readfirstlane(__float_as_uint(beta)));
        beta *= (1.0f / r);
        M += __logf(r);
    }

    num += endT[prev];

    // denominator = M + log(sum_j beta_j * exp(end_j))
    float v = beta * eend;
#pragma unroll
    for (int off = 32; off > 0; off >>= 1)
        v += __shfl_xor(v, off);
    float denom = M + __logf(v);

    if (j == 0)
        atomicAdd(out, num - denom);
}

extern "C" void kernel_launch(void* const* d_in, const int* in_sizes, int n_in,
                              void* d_out, int out_size, void* d_ws, size_t ws_size,
                              hipStream_t stream)
{
    const float* em     = (const float*)d_in[0];
    const int*   tags   = (const int*)d_in[1];
    const int*   mask   = (const int*)d_in[2];
    const float* startT = (const float*)d_in[3];
    const float* endT   = (const float*)d_in[4];
    const float* trans  = (const float*)d_in[5];
    float*       out    = (float*)d_out;

    hipMemsetAsync(out, 0, sizeof(float) * out_size, stream);
    crf_kernel<<<BATCH, 64, 0, stream>>>(em, tags, mask, startT, endT, trans, out);
}

// Round 5
// 276.448 us; speedup vs baseline: 1.8016x; 1.8016x over previous
//
#include <hip/hip_runtime.h>

#define SEQ 1024
#define BATCH 512
#define NTAGS 64
#define HALF_T 512
#define LOGD 4.158883083f   // log(64): per-step damp folded into exp(em)

typedef _Float16 v2h __attribute__((ext_vector_type(2)));

// Compiler-only ordering fence: single-wave lockstep + in-order DS pipe means
// no s_barrier is needed, just stop compiler reordering around LDS ops.
#define FENCE() asm volatile("" ::: "memory")

__device__ __forceinline__ float dot2acc(v2h a, v2h b, float c) {
#if __has_builtin(__builtin_amdgcn_fdot2)
    return __builtin_amdgcn_fdot2(a, b, c, false);
#else
    return fmaf((float)a.x, (float)b.x, fmaf((float)a.y, (float)b.y, c));
#endif
}

__device__ __forceinline__ float rfl(float x) {
    return __uint_as_float(__builtin_amdgcn_readfirstlane(__float_as_uint(x)));
}

// Scan: block < BATCH -> forward chain b over t=1..min(L-1,511);
//       block >= BATCH -> backward chain b over t=L-1..512 (descending).
// Linear space with per-step damp 1/64 and a renorm every 4 steps by
// r = readfirstlane(dot) (dot output is lane-uniform to +-10% => cheap,
// wave-uniform, positive scale). True vector = stored * exp(M_out).
__global__ __launch_bounds__(64)
void scan_kernel(const float* __restrict__ em,
                 const int* __restrict__ mask,
                 const float* __restrict__ startT,
                 const float* __restrict__ endT,
                 const float* __restrict__ trans,
                 float* __restrict__ beta_f, float* __restrict__ Mf,
                 float* __restrict__ gma,    float* __restrict__ Mb,
                 int* __restrict__ Lw)
{
    const bool fwd = blockIdx.x < BATCH;
    const int  b   = fwd ? blockIdx.x : blockIdx.x - BATCH;
    const int  j   = threadIdx.x;

    __shared__ __align__(16) _Float16 bsh[NTAGS];

    // chain length = sum of (prefix) mask column
    int lsum = 0;
#pragma unroll
    for (int k = 0; k < SEQ / 64; ++k)
        lsum += mask[(k * 64 + j) * BATCH + b];
#pragma unroll
    for (int off = 32; off > 0; off >>= 1)
        lsum += __shfl_xor(lsum, off);
    const int L = lsum;

    // fp16 expT fragment: fwd lane j = column j (paired over i);
    // bwd lane j = row j (paired over k).
    v2h w[32];
#pragma unroll
    for (int i = 0; i < 32; ++i) {
        float a0, a1;
        if (fwd) { a0 = trans[(2 * i) * NTAGS + j]; a1 = trans[(2 * i + 1) * NTAGS + j]; }
        else     { a0 = trans[j * NTAGS + 2 * i];   a1 = trans[j * NTAGS + 2 * i + 1];   }
        v2h t; t.x = (_Float16)__expf(a0); t.y = (_Float16)__expf(a1);
        w[i] = t;
    }

    const float4* bv = (const float4*)bsh;

#define DOT(WRVAL, SOUT)                                                   \
    {                                                                      \
        FENCE();                                                           \
        bsh[j] = (_Float16)(WRVAL);                                        \
        FENCE();                                                           \
        float s0 = 0.f, s1 = 0.f, s2 = 0.f, s3 = 0.f;                      \
        _Pragma("unroll")                                                  \
        for (int q4 = 0; q4 < 8; ++q4) {                                   \
            float4 q = bv[q4];                                             \
            s0 = dot2acc(__builtin_bit_cast(v2h, q.x), w[4 * q4 + 0], s0); \
            s1 = dot2acc(__builtin_bit_cast(v2h, q.y), w[4 * q4 + 1], s1); \
            s2 = dot2acc(__builtin_bit_cast(v2h, q.z), w[4 * q4 + 2], s2); \
            s3 = dot2acc(__builtin_bit_cast(v2h, q.w), w[4 * q4 + 3], s3); \
        }                                                                  \
        SOUT = (s0 + s1) + (s2 + s3);                                      \
    }

    float beta, M;
    int nsteps = 0;

    if (fwd) {
        float em0 = em[(size_t)b * NTAGS + j];
        float a0  = startT[j] + em0;
        M    = __shfl(a0, 0);
        beta = __expf(a0 - M);

        const int Lf = min(L - 1, HALF_T - 1);   // active steps t=1..Lf
        int t = 1;
        float cur[4], nxt[4];
#pragma unroll
        for (int u = 0; u < 4; ++u) {
            cur[u] = em[((size_t)min(t + u,     SEQ - 1) * BATCH + b) * NTAGS + j];
            nxt[u] = em[((size_t)min(t + 4 + u, SEQ - 1) * BATCH + b) * NTAGS + j];
        }
        while (t + 3 <= Lf) {
            float pre[4];
#pragma unroll
            for (int u = 0; u < 4; ++u)
                pre[u] = em[((size_t)min(t + 8 + u, SEQ - 1) * BATCH + b) * NTAGS + j];
            float eem[4];
#pragma unroll
            for (int u = 0; u < 4; ++u) eem[u] = __expf(cur[u] - LOGD);

            float s;
            DOT(beta, s); beta = s * eem[0];
            DOT(beta, s);
            float r = rfl(s);                 // uniform, ~Sigma(beta): renorm scale
            beta = s * eem[1];
            DOT(beta, s); beta = s * eem[2];
            float rinv = 1.0f / r;            // off-path
            float lr   = __logf(r);           // off-path
            DOT(beta, s); beta = s * (eem[3] * rinv);
            M += lr;
            nsteps += 4;
#pragma unroll
            for (int u = 0; u < 4; ++u) { cur[u] = nxt[u]; nxt[u] = pre[u]; }
            t += 4;
        }
        for (; t <= Lf; ++t) {
            float emt = em[((size_t)t * BATCH + b) * NTAGS + j];
            float s; DOT(beta, s);
            beta = s * __expf(emt - LOGD);
            ++nsteps;
        }

        beta_f[b * NTAGS + j] = beta;
        if (j == 0) {
            Mf[b] = fmaf((float)nsteps, LOGD, M);
            Lw[b] = L;
        }
    } else {
        beta = __expf(endT[j]);               // B_j init (frozen for t >= L)
        M = 0.0f;
        if (L - 1 >= HALF_T) {
            int tt = L - 1;                   // steps tt = L-1 .. 512 descending
            float cur[4], nxt[4];
#pragma unroll
            for (int u = 0; u < 4; ++u) {
                cur[u] = em[((size_t)max(tt - u,     0) * BATCH + b) * NTAGS + j];
                nxt[u] = em[((size_t)max(tt - 4 - u, 0) * BATCH + b) * NTAGS + j];
            }
            while (tt - 3 >= HALF_T) {
                float pre[4];
#pragma unroll
                for (int u = 0; u < 4; ++u)
                    pre[u] = em[((size_t)max(tt - 8 - u, 0) * BATCH + b) * NTAGS + j];
                float eem[4];
#pragma unroll
                for (int u = 0; u < 4; ++u) eem[u] = __expf(cur[u] - LOGD);

                float s;
                DOT(beta * eem[0], s); beta = s;
                DOT(beta * eem[1], s);
                float r = rfl(s);
                beta = s;
                DOT(beta * eem[2], s); beta = s;
                float rinv = 1.0f / r;
                float lr   = __logf(r);
                DOT(beta * (eem[3] * rinv), s); beta = s;
                M += lr;
                nsteps += 4;
#pragma unroll
                for (int u = 0; u < 4; ++u) { cur[u] = nxt[u]; nxt[u] = pre[u]; }
                tt -= 4;
            }
            for (; tt >= HALF_T; --tt) {
                float emt = em[((size_t)tt * BATCH + b) * NTAGS + j];
                float s; DOT(beta * __expf(emt - LOGD), s);
                beta = s;
                ++nsteps;
            }
        }
        gma[b * NTAGS + j] = beta;
        if (j == 0)
            Mb[b] = fmaf((float)nsteps, LOGD, M);
    }
#undef DOT
}

// Join: per chain, numerator (fully parallel masked gather-sum) + the
// midpoint dot Z = log(sum_j beta_j * B_j) + Mf + Mb; accumulate llh.
__global__ __launch_bounds__(64)
void join_kernel(const float* __restrict__ em,
                 const int* __restrict__ tags,
                 const float* __restrict__ startT,
                 const float* __restrict__ endT,
                 const float* __restrict__ trans,
                 const float* __restrict__ beta_f, const float* __restrict__ Mf,
                 const float* __restrict__ gma,    const float* __restrict__ Mb,
                 const int* __restrict__ Lw,
                 float* __restrict__ out)
{
    const int b = blockIdx.x;
    const int j = threadIdx.x;

    __shared__ float tr_sh[NTAGS * NTAGS];
#pragma unroll
    for (int i = 0; i < NTAGS; ++i)
        tr_sh[i * NTAGS + j] = trans[i * NTAGS + j];
    __syncthreads();

    const int L = Lw[b];

    // numerator partial: lane j handles t = j, j+64, ...
    float np = 0.0f;
#pragma unroll
    for (int k = 0; k < SEQ / 64; ++k) {
        int t = k * 64 + j;
        if (t >= 1 && t < L) {
            int ct = tags[t * BATCH + b];
            int pt = tags[(t - 1) * BATCH + b];
            np += tr_sh[pt * NTAGS + ct] + em[((size_t)t * BATCH + b) * NTAGS + ct];
        }
    }
    if (j == 0) {
        int t0 = tags[b];
        np += startT[t0] + em[(size_t)b * NTAGS + t0]
            + endT[tags[(size_t)(L - 1) * BATCH + b]];
    }

    float p = beta_f[b * NTAGS + j] * gma[b * NTAGS + j];

#pragma unroll
    for (int off = 32; off > 0; off >>= 1) {
        np += __shfl_xor(np, off);
        p  += __shfl_xor(p,  off);
    }

    if (j == 0) {
        float denom = __logf(p) + Mf[b] + Mb[b];
        atomicAdd(out, np - denom);
    }
}

extern "C" void kernel_launch(void* const* d_in, const int* in_sizes, int n_in,
                              void* d_out, int out_size, void* d_ws, size_t ws_size,
                              hipStream_t stream)
{
    const float* em     = (const float*)d_in[0];
    const int*   tags   = (const int*)d_in[1];
    const int*   mask   = (const int*)d_in[2];
    const float* startT = (const float*)d_in[3];
    const float* endT   = (const float*)d_in[4];
    const float* trans  = (const float*)d_in[5];
    float*       out    = (float*)d_out;

    float* beta_f = (float*)d_ws;                 // 512*64
    float* Mf     = beta_f + BATCH * NTAGS;       // 512
    float* gma    = Mf + BATCH;                   // 512*64
    float* Mb     = gma + BATCH * NTAGS;          // 512
    int*   Lw     = (int*)(Mb + BATCH);           // 512

    hipMemsetAsync(out, 0, sizeof(float) * out_size, stream);
    scan_kernel<<<2 * BATCH, 64, 0, stream>>>(em, mask, startT, endT, trans,
                                              beta_f, Mf, gma, Mb, Lw);
    join_kernel<<<BATCH, 64, 0, stream>>>(em, tags, startT, endT, trans,
                                          beta_f, Mf, gma, Mb, Lw, out);
}